// Round 2
// baseline (1159.262 us; speedup 1.0000x reference)
//
#include <hip/hip_runtime.h>

#define N_USER 100000
#define N_ITEM 100000
#define N_NODES 200000
#define NNZ 6400000
#define EMB 64
#define BATCH 1024

// ---------------------------------------------------------------------------
// Workspace layout:
//   ego     : N_NODES*EMB f32   (51.2 MB)  current layer embeddings (master)
//   side    : N_NODES*EMB f32   (51.2 MB)  spmm output
//   ego_h   : N_NODES*EMB bf16  (25.6 MB)  bf16 mirror of ego for the gather
//   row_ptr : N_NODES+1 ints    (0.8 MB)   CSR row starts (adj_row is sorted)
// ---------------------------------------------------------------------------

__device__ __forceinline__ float readlane_f(float v, int lane) {
    return __builtin_bit_cast(float,
        __builtin_amdgcn_readlane(__builtin_bit_cast(int, v), lane));
}

// f32 -> bf16 (RNE), raw ushort bits
__device__ __forceinline__ unsigned short f2bf(float f) {
    unsigned int b = __builtin_bit_cast(unsigned int, f);
    b += 0x7FFFu + ((b >> 16) & 1u);
    return (unsigned short)(b >> 16);
}
__device__ __forceinline__ float bf2f(unsigned short u) {
    return __builtin_bit_cast(float, (unsigned int)u << 16);
}

// row_ptr[r] = lower_bound(adj_row, r); every r in [0, N_NODES] written once.
__global__ void build_row_ptr(const int* __restrict__ row, int* __restrict__ row_ptr) {
    int i = blockIdx.x * blockDim.x + threadIdx.x;
    if (i >= NNZ) return;
    int b = row[i];
    int a = (i == 0) ? -1 : row[i - 1];
    for (int r = a + 1; r <= b; ++r) row_ptr[r] = i;
    if (i == NNZ - 1) {
        for (int r = b + 1; r <= N_NODES; ++r) row_ptr[r] = NNZ;
    }
}

// ego = [user_emb ; item_emb] (f32) + bf16 mirror
__global__ void concat_ego(const float* __restrict__ ue, const float* __restrict__ ie,
                           float* __restrict__ ego, unsigned short* __restrict__ ego_h) {
    int i = blockIdx.x * blockDim.x + threadIdx.x;   // element index
    if (i >= N_NODES * EMB) return;
    const int nu = N_USER * EMB;
    float v = (i < nu) ? ue[i] : ie[i - nu];
    ego[i] = v;
    ego_h[i] = f2bf(v);
}

__device__ __forceinline__ int batch_node(const int* users, const int* pos,
                                          const int* neg, int b) {
    int t = b >> 10, idx = b & 1023;
    if (t == 0) return users[idx];
    if (t == 1) return N_USER + pos[idx];
    return N_USER + neg[idx];
}

// layer-0 columns of the output: raw concatenated embeddings, gathered (exact f32)
__global__ void gather_layer0(const int* __restrict__ users, const int* __restrict__ pos,
                              const int* __restrict__ neg, const float* __restrict__ ego,
                              float* __restrict__ out) {
    int b = blockIdx.x;                 // 0..3071
    int node = batch_node(users, pos, neg, b);
    out[(size_t)b * 256 + threadIdx.x] = ego[(size_t)node * EMB + threadIdx.x];
}

// CSR SpMM: one wave per row, lane = embedding dim. x gathered in bf16
// (128 B/nnz instead of 256 B), accumulate f32. col/val are streaming:
// non-temporal so they don't evict gather lines from L2.
__global__ __launch_bounds__(256) void spmm_csr(
        const int* __restrict__ row_ptr, const int* __restrict__ col,
        const float* __restrict__ val, const unsigned short* __restrict__ xh,
        float* __restrict__ y) {
    int wave = (blockIdx.x * blockDim.x + threadIdx.x) >> 6;
    int lane = threadIdx.x & 63;
    if (wave >= N_NODES) return;
    int j0 = row_ptr[wave], j1 = row_ptr[wave + 1];
    float acc = 0.f;
    int j = j0;
    for (; j + 8 <= j1; j += 8) {
        int   c[8];
        float v[8];
#pragma unroll
        for (int t = 0; t < 8; ++t) {
            c[t] = __builtin_nontemporal_load(col + j + t);
            v[t] = __builtin_nontemporal_load(val + j + t);
        }
#pragma unroll
        for (int t = 0; t < 8; ++t) {
            float x = bf2f(xh[(size_t)c[t] * EMB + lane]);
            acc = fmaf(v[t], x, acc);
        }
    }
    for (; j < j1; ++j)
        acc = fmaf(val[j], bf2f(xh[(size_t)col[j] * EMB + lane]), acc);
    y[(size_t)wave * EMB + lane] = acc;
}

// ego <- leaky_relu(side@Wgc + bgc + (ego*side)@Wbi + bbi), in place; also
// refresh the bf16 mirror. One wave per row (grid-stride). Each lane holds one
// output column of both weight matrices in VGPRs; rows broadcast via readlane.
__global__ __launch_bounds__(256) void dense_layer(
        float* __restrict__ ego, unsigned short* __restrict__ ego_h,
        const float* __restrict__ side,
        const float* __restrict__ Wgc, const float* __restrict__ bgc,
        const float* __restrict__ Wbi, const float* __restrict__ bbi) {
    int lane = threadIdx.x & 63;
    float wgc[EMB], wbi[EMB];
#pragma unroll
    for (int k = 0; k < EMB; ++k) {
        wgc[k] = Wgc[k * EMB + lane];    // column `lane`
        wbi[k] = Wbi[k * EMB + lane];
    }
    float bg = bgc[lane], bb = bbi[lane];

    int wave   = (blockIdx.x * blockDim.x + threadIdx.x) >> 6;
    int nwaves = (gridDim.x * blockDim.x) >> 6;
    for (int r = wave; r < N_NODES; r += nwaves) {
        float sv = side[(size_t)r * EMB + lane];
        float ev = ego[(size_t)r * EMB + lane];
        float pv = ev * sv;
        float a1 = bg, a2 = bb;
#pragma unroll
        for (int k = 0; k < EMB; ++k) {
            a1 += readlane_f(sv, k) * wgc[k];
            a2 += readlane_f(pv, k) * wbi[k];
        }
        float c = a1 + a2;
        float o = c > 0.f ? c : 0.2f * c;
        ego[(size_t)r * EMB + lane] = o;   // row fully read before write: safe
        ego_h[(size_t)r * EMB + lane] = f2bf(o);
    }
}

// gather batch rows of ego (f32), L2-normalize, write out cols [64*layer, ...)
__global__ void gather_norm(const int* __restrict__ users, const int* __restrict__ pos,
                            const int* __restrict__ neg, const float* __restrict__ ego,
                            float* __restrict__ out, int layer) {
    int b = blockIdx.x;                 // 0..3071
    int lane = threadIdx.x;             // 0..63
    int node = batch_node(users, pos, neg, b);
    float v = ego[(size_t)node * EMB + lane];
    float s = v * v;
#pragma unroll
    for (int off = 32; off > 0; off >>= 1) s += __shfl_xor(s, off);
    float n = fmaxf(sqrtf(s), 1e-12f);
    out[(size_t)b * 256 + layer * EMB + lane] = v / n;
}

extern "C" void kernel_launch(void* const* d_in, const int* in_sizes, int n_in,
                              void* d_out, int out_size, void* d_ws, size_t ws_size,
                              hipStream_t stream) {
    const int*   users    = (const int*)d_in[0];
    const int*   pos      = (const int*)d_in[1];
    const int*   neg      = (const int*)d_in[2];
    const int*   adj_row  = (const int*)d_in[3];
    const int*   adj_col  = (const int*)d_in[4];
    const float* adj_val  = (const float*)d_in[5];
    const float* user_emb = (const float*)d_in[6];
    const float* item_emb = (const float*)d_in[7];
    // d_in[8..19]: W_gc_0, b_gc_0, W_bi_0, b_bi_0, W_gc_1, ... (4 per layer)

    float*          ego     = (float*)d_ws;
    float*          side    = ego + (size_t)N_NODES * EMB;
    unsigned short* ego_h   = (unsigned short*)(side + (size_t)N_NODES * EMB);
    int*            row_ptr = (int*)(ego_h + (size_t)N_NODES * EMB);
    float*          out     = (float*)d_out;

    build_row_ptr<<<(NNZ + 255) / 256, 256, 0, stream>>>(adj_row, row_ptr);
    concat_ego<<<(N_NODES * EMB + 255) / 256, 256, 0, stream>>>(user_emb, item_emb, ego, ego_h);
    gather_layer0<<<3 * BATCH, 64, 0, stream>>>(users, pos, neg, ego, out);

    for (int k = 0; k < 3; ++k) {
        const float* Wgc = (const float*)d_in[8 + 4 * k];
        const float* bgc = (const float*)d_in[9 + 4 * k];
        const float* Wbi = (const float*)d_in[10 + 4 * k];
        const float* bbi = (const float*)d_in[11 + 4 * k];
        spmm_csr<<<N_NODES / 4, 256, 0, stream>>>(row_ptr, adj_col, adj_val, ego_h, side);
        dense_layer<<<2048, 256, 0, stream>>>(ego, ego_h, side, Wgc, bgc, Wbi, bbi);
        gather_norm<<<3 * BATCH, 64, 0, stream>>>(users, pos, neg, ego, out, k + 1);
    }
}

// Round 3
// 816.706 us; speedup vs baseline: 1.4194x; 1.4194x over previous
//
#include <hip/hip_runtime.h>

#define N_USER 100000
#define N_ITEM 100000
#define N_NODES 200000
#define NNZ 6400000
#define EMB 64
#define BATCH 1024

// ---------------------------------------------------------------------------
// Workspace layout:
//   ego     : N_NODES*EMB f32   (51.2 MB)  current layer embeddings (master)
//   side    : N_NODES*EMB f32   (51.2 MB)  spmm output
//   ego_h   : N_NODES*EMB bf16  (25.6 MB)  bf16 mirror of ego for the gather
//   row_ptr : N_NODES+1 ints    (0.8 MB)   CSR row starts (adj_row is sorted)
// ---------------------------------------------------------------------------

__device__ __forceinline__ float readlane_f(float v, int lane) {
    return __builtin_bit_cast(float,
        __builtin_amdgcn_readlane(__builtin_bit_cast(int, v), lane));
}

// f32 -> bf16 (RNE), raw ushort bits
__device__ __forceinline__ unsigned short f2bf(float f) {
    unsigned int b = __builtin_bit_cast(unsigned int, f);
    b += 0x7FFFu + ((b >> 16) & 1u);
    return (unsigned short)(b >> 16);
}
__device__ __forceinline__ float bf2f(unsigned short u) {
    return __builtin_bit_cast(float, (unsigned int)u << 16);
}

// row_ptr[r] = lower_bound(adj_row, r); every r in [0, N_NODES] written once.
__global__ void build_row_ptr(const int* __restrict__ row, int* __restrict__ row_ptr) {
    int i = blockIdx.x * blockDim.x + threadIdx.x;
    if (i >= NNZ) return;
    int b = row[i];
    int a = (i == 0) ? -1 : row[i - 1];
    for (int r = a + 1; r <= b; ++r) row_ptr[r] = i;
    if (i == NNZ - 1) {
        for (int r = b + 1; r <= N_NODES; ++r) row_ptr[r] = NNZ;
    }
}

// ego = [user_emb ; item_emb] (f32) + bf16 mirror
__global__ void concat_ego(const float* __restrict__ ue, const float* __restrict__ ie,
                           float* __restrict__ ego, unsigned short* __restrict__ ego_h) {
    int i = blockIdx.x * blockDim.x + threadIdx.x;   // element index
    if (i >= N_NODES * EMB) return;
    const int nu = N_USER * EMB;
    float v = (i < nu) ? ue[i] : ie[i - nu];
    ego[i] = v;
    ego_h[i] = f2bf(v);
}

__device__ __forceinline__ int batch_node(const int* users, const int* pos,
                                          const int* neg, int b) {
    int t = b >> 10, idx = b & 1023;
    if (t == 0) return users[idx];
    if (t == 1) return N_USER + pos[idx];
    return N_USER + neg[idx];
}

// layer-0 columns of the output: raw concatenated embeddings, gathered (exact f32)
__global__ void gather_layer0(const int* __restrict__ users, const int* __restrict__ pos,
                              const int* __restrict__ neg, const float* __restrict__ ego,
                              float* __restrict__ out) {
    int b = blockIdx.x;                 // 0..3071
    int node = batch_node(users, pos, neg, b);
    out[(size_t)b * 256 + threadIdx.x] = ego[(size_t)node * EMB + threadIdx.x];
}

// CSR SpMM: one wave per row, lane = embedding dim, x gathered in bf16.
// Per 32-nnz chunk: ONE coalesced col load + ONE val load (lanes &31), then
// readlane broadcast (SGPR) -> gather address is SALU + global_load_ushort.
// vmem per nnz ~1 instead of 3 (this kernel is vmem-ISSUE bound, not BW bound).
// OOB nnz in a chunk carry val=0/col=0 -> fma adds 0; wave-uniform early exit
// every 8 nnz bounds the waste.
__global__ __launch_bounds__(256) void spmm_csr(
        const int* __restrict__ row_ptr, const int* __restrict__ col,
        const float* __restrict__ val, const unsigned short* __restrict__ xh,
        float* __restrict__ y) {
    int wave = (blockIdx.x * blockDim.x + threadIdx.x) >> 6;
    int lane = threadIdx.x & 63;
    if (wave >= N_NODES) return;
    int j0 = row_ptr[wave], j1 = row_ptr[wave + 1];
    float acc0 = 0.f, acc1 = 0.f;
    for (int j = j0; j < j1; j += 32) {
        int jl = j + (lane & 31);           // lanes 32..63 duplicate 0..31: same lines
        bool ok = jl < j1;
        int   c = ok ? col[jl] : 0;
        float v = ok ? val[jl] : 0.f;
        int n = j1 - j;                     // nnz remaining in this chunk (may be >32)
#pragma unroll
        for (int g = 0; g < 4; ++g) {
            if (g * 8 >= n) break;          // wave-uniform exit
#pragma unroll
            for (int u = 0; u < 8; ++u) {
                const int t = g * 8 + u;
                int   ct = __builtin_amdgcn_readlane(c, t);            // SGPR
                float vt = readlane_f(v, t);                           // SGPR
                float x  = bf2f(xh[(size_t)ct * EMB + lane]);
                if (u & 1) acc1 = fmaf(vt, x, acc1);
                else       acc0 = fmaf(vt, x, acc0);
            }
        }
    }
    y[(size_t)wave * EMB + lane] = acc0 + acc1;
}

// ego <- leaky_relu(side@Wgc + bgc + (ego*side)@Wbi + bbi), in place; also
// refresh the bf16 mirror. One wave per row (grid-stride). Each lane holds one
// output column of both weight matrices in VGPRs; rows broadcast via readlane.
__global__ __launch_bounds__(256) void dense_layer(
        float* __restrict__ ego, unsigned short* __restrict__ ego_h,
        const float* __restrict__ side,
        const float* __restrict__ Wgc, const float* __restrict__ bgc,
        const float* __restrict__ Wbi, const float* __restrict__ bbi) {
    int lane = threadIdx.x & 63;
    float wgc[EMB], wbi[EMB];
#pragma unroll
    for (int k = 0; k < EMB; ++k) {
        wgc[k] = Wgc[k * EMB + lane];    // column `lane`
        wbi[k] = Wbi[k * EMB + lane];
    }
    float bg = bgc[lane], bb = bbi[lane];

    int wave   = (blockIdx.x * blockDim.x + threadIdx.x) >> 6;
    int nwaves = (gridDim.x * blockDim.x) >> 6;
    for (int r = wave; r < N_NODES; r += nwaves) {
        float sv = side[(size_t)r * EMB + lane];
        float ev = ego[(size_t)r * EMB + lane];
        float pv = ev * sv;
        float a1 = bg, a2 = bb;
#pragma unroll
        for (int k = 0; k < EMB; ++k) {
            a1 += readlane_f(sv, k) * wgc[k];
            a2 += readlane_f(pv, k) * wbi[k];
        }
        float c = a1 + a2;
        float o = c > 0.f ? c : 0.2f * c;
        ego[(size_t)r * EMB + lane] = o;   // row fully read before write: safe
        ego_h[(size_t)r * EMB + lane] = f2bf(o);
    }
}

// gather batch rows of ego (f32), L2-normalize, write out cols [64*layer, ...)
__global__ void gather_norm(const int* __restrict__ users, const int* __restrict__ pos,
                            const int* __restrict__ neg, const float* __restrict__ ego,
                            float* __restrict__ out, int layer) {
    int b = blockIdx.x;                 // 0..3071
    int lane = threadIdx.x;             // 0..63
    int node = batch_node(users, pos, neg, b);
    float v = ego[(size_t)node * EMB + lane];
    float s = v * v;
#pragma unroll
    for (int off = 32; off > 0; off >>= 1) s += __shfl_xor(s, off);
    float n = fmaxf(sqrtf(s), 1e-12f);
    out[(size_t)b * 256 + layer * EMB + lane] = v / n;
}

extern "C" void kernel_launch(void* const* d_in, const int* in_sizes, int n_in,
                              void* d_out, int out_size, void* d_ws, size_t ws_size,
                              hipStream_t stream) {
    const int*   users    = (const int*)d_in[0];
    const int*   pos      = (const int*)d_in[1];
    const int*   neg      = (const int*)d_in[2];
    const int*   adj_row  = (const int*)d_in[3];
    const int*   adj_col  = (const int*)d_in[4];
    const float* adj_val  = (const float*)d_in[5];
    const float* user_emb = (const float*)d_in[6];
    const float* item_emb = (const float*)d_in[7];
    // d_in[8..19]: W_gc_0, b_gc_0, W_bi_0, b_bi_0, W_gc_1, ... (4 per layer)

    float*          ego     = (float*)d_ws;
    float*          side    = ego + (size_t)N_NODES * EMB;
    unsigned short* ego_h   = (unsigned short*)(side + (size_t)N_NODES * EMB);
    int*            row_ptr = (int*)(ego_h + (size_t)N_NODES * EMB);
    float*          out     = (float*)d_out;

    build_row_ptr<<<(NNZ + 255) / 256, 256, 0, stream>>>(adj_row, row_ptr);
    concat_ego<<<(N_NODES * EMB + 255) / 256, 256, 0, stream>>>(user_emb, item_emb, ego, ego_h);
    gather_layer0<<<3 * BATCH, 64, 0, stream>>>(users, pos, neg, ego, out);

    for (int k = 0; k < 3; ++k) {
        const float* Wgc = (const float*)d_in[8 + 4 * k];
        const float* bgc = (const float*)d_in[9 + 4 * k];
        const float* Wbi = (const float*)d_in[10 + 4 * k];
        const float* bbi = (const float*)d_in[11 + 4 * k];
        spmm_csr<<<N_NODES / 4, 256, 0, stream>>>(row_ptr, adj_col, adj_val, ego_h, side);
        dense_layer<<<2048, 256, 0, stream>>>(ego, ego_h, side, Wgc, bgc, Wbi, bbi);
        gather_norm<<<3 * BATCH, 64, 0, stream>>>(users, pos, neg, ego, out, k + 1);
    }
}

// Round 4
// 625.539 us; speedup vs baseline: 1.8532x; 1.3056x over previous
//
#include <hip/hip_runtime.h>

#define N_USER 100000
#define N_ITEM 100000
#define N_NODES 200000
#define NNZ 6400000
#define EMB 64
#define BATCH 1024

typedef __attribute__((ext_vector_type(8))) short bf16x8;   // 8 bf16 = 4 VGPRs
typedef __attribute__((ext_vector_type(4))) float f32x4;    // MFMA 16x16 acc

// ---------------------------------------------------------------------------
// Workspace layout:
//   ego     : N_NODES*EMB f32   (51.2 MB) f32 layer output (read by gather_norm)
//   ego_h   : N_NODES*EMB bf16  (25.6 MB) bf16 master state (spmm gather + dense A)
//   side_h  : N_NODES*EMB bf16  (25.6 MB) spmm output, bf16
//   row_ptr : padded to 200704 ints       CSR row starts (adj_row is sorted)
//   wfrag   : 6*8*64*8 bf16     (48 KB)   weights pre-packed into B-fragments
// ---------------------------------------------------------------------------

__device__ __forceinline__ float readlane_f(float v, int lane) {
    return __builtin_bit_cast(float,
        __builtin_amdgcn_readlane(__builtin_bit_cast(int, v), lane));
}

// f32 -> bf16 (RNE), raw ushort bits
__device__ __forceinline__ unsigned short f2bf(float f) {
    unsigned int b = __builtin_bit_cast(unsigned int, f);
    b += 0x7FFFu + ((b >> 16) & 1u);
    return (unsigned short)(b >> 16);
}
__device__ __forceinline__ float bf2f(unsigned short u) {
    return __builtin_bit_cast(float, (unsigned int)u << 16);
}

// elementwise product of two bf16 fragments (A-layouts align), f32 math
__device__ __forceinline__ bf16x8 mul_bf(bf16x8 a, bf16x8 b) {
    bf16x8 r;
#pragma unroll
    for (int j = 0; j < 8; ++j) {
        float f = bf2f((unsigned short)a[j]) * bf2f((unsigned short)b[j]);
        r[j] = (short)f2bf(f);
    }
    return r;
}

// row_ptr[r] = lower_bound(adj_row, r); every r in [0, N_NODES] written once.
__global__ void build_row_ptr(const int* __restrict__ row, int* __restrict__ row_ptr) {
    int i = blockIdx.x * blockDim.x + threadIdx.x;
    if (i >= NNZ) return;
    int b = row[i];
    int a = (i == 0) ? -1 : row[i - 1];
    for (int r = a + 1; r <= b; ++r) row_ptr[r] = i;
    if (i == NNZ - 1) {
        for (int r = b + 1; r <= N_NODES; ++r) row_ptr[r] = NNZ;
    }
}

// ego = [user_emb ; item_emb] (f32) + bf16 mirror
__global__ void concat_ego(const float* __restrict__ ue, const float* __restrict__ ie,
                           float* __restrict__ ego, unsigned short* __restrict__ ego_h) {
    int i = blockIdx.x * blockDim.x + threadIdx.x;
    if (i >= N_NODES * EMB) return;
    const int nu = N_USER * EMB;
    float v = (i < nu) ? ue[i] : ie[i - nu];
    ego[i] = v;
    ego_h[i] = f2bf(v);
}

// pack the 6 64x64 f32 weight matrices into MFMA B-fragment layout (bf16).
// blockIdx = m*8 + t*2 + c; lane holds B[k=c*32+quad*8+j][n=t*16+(lane&15)].
__global__ void prep_wfrags(const float* __restrict__ W0, const float* __restrict__ W1,
                            const float* __restrict__ W2, const float* __restrict__ W3,
                            const float* __restrict__ W4, const float* __restrict__ W5,
                            unsigned short* __restrict__ wfrag) {
    int m = blockIdx.x >> 3;
    int t = (blockIdx.x >> 1) & 3, c = blockIdx.x & 1;
    const float* W = m == 0 ? W0 : m == 1 ? W1 : m == 2 ? W2 : m == 3 ? W3 : m == 4 ? W4 : W5;
    int l = threadIdx.x, quad = l >> 4, n = l & 15;
    unsigned short* dst = wfrag + ((size_t)blockIdx.x * 64 + l) * 8;
#pragma unroll
    for (int j = 0; j < 8; ++j)
        dst[j] = f2bf(W[(c * 32 + quad * 8 + j) * 64 + t * 16 + n]);
}

__device__ __forceinline__ int batch_node(const int* users, const int* pos,
                                          const int* neg, int b) {
    int t = b >> 10, idx = b & 1023;
    if (t == 0) return users[idx];
    if (t == 1) return N_USER + pos[idx];
    return N_USER + neg[idx];
}

// layer-0 columns of the output: raw concatenated embeddings, gathered (exact f32)
__global__ void gather_layer0(const int* __restrict__ users, const int* __restrict__ pos,
                              const int* __restrict__ neg, const float* __restrict__ ego,
                              float* __restrict__ out) {
    int b = blockIdx.x;
    int node = batch_node(users, pos, neg, b);
    out[(size_t)b * 256 + threadIdx.x] = ego[(size_t)node * EMB + threadIdx.x];
}

// CSR SpMM: one wave per row, lane = embedding dim, x gathered in bf16.
// Per 32-nnz chunk: ONE coalesced col load + ONE val load (lanes &31), then
// readlane broadcast (SGPR) -> gather address is SALU + global_load_ushort.
// Output written as bf16 (dense consumes bf16 fragments directly).
__global__ __launch_bounds__(256) void spmm_csr(
        const int* __restrict__ row_ptr, const int* __restrict__ col,
        const float* __restrict__ val, const unsigned short* __restrict__ xh,
        unsigned short* __restrict__ yh) {
    int wave = (blockIdx.x * blockDim.x + threadIdx.x) >> 6;
    int lane = threadIdx.x & 63;
    if (wave >= N_NODES) return;
    int j0 = row_ptr[wave], j1 = row_ptr[wave + 1];
    float acc0 = 0.f, acc1 = 0.f;
    for (int j = j0; j < j1; j += 32) {
        int jl = j + (lane & 31);           // lanes 32..63 duplicate 0..31: same lines
        bool ok = jl < j1;
        int   c = ok ? col[jl] : 0;
        float v = ok ? val[jl] : 0.f;
        int n = j1 - j;
#pragma unroll
        for (int g = 0; g < 4; ++g) {
            if (g * 8 >= n) break;          // wave-uniform exit
#pragma unroll
            for (int u = 0; u < 8; ++u) {
                const int t = g * 8 + u;
                int   ct = __builtin_amdgcn_readlane(c, t);            // SGPR
                float vt = readlane_f(v, t);                           // SGPR
                float x  = bf2f(xh[(size_t)ct * EMB + lane]);
                if (u & 1) acc1 = fmaf(vt, x, acc1);
                else       acc0 = fmaf(vt, x, acc0);
            }
        }
    }
    yh[(size_t)wave * EMB + lane] = f2bf(acc0 + acc1);
}

// MFMA dense layer: ego <- leaky_relu(side@Wgc + bgc + (ego*side)@Wbi + bbi).
// Wave = 16 rows x 64 cols; 4 n-tiles x 2 k-chunks x 2 matmuls = 16 MFMA into
// one bias-initialized accumulator. A-frag = 16B contiguous bf16 load
// (A[m=lane&15][k=quad*8+j]); pv computed elementwise in fragment space.
// In-place ego_h update is safe: each row read+written by exactly one wave.
__global__ __launch_bounds__(256) void dense_mfma(
        const unsigned short* __restrict__ side_h,
        unsigned short* __restrict__ ego_h,
        float* __restrict__ ego,
        const unsigned short* __restrict__ wf,   // this layer: [m][t][c][lane][8]
        const float* __restrict__ bgc, const float* __restrict__ bbi) {
    int wave = threadIdx.x >> 6;
    int lane = threadIdx.x & 63;
    int quad = lane >> 4, n = lane & 15;
    int r0 = blockIdx.x * 64 + wave * 16;

    // B fragments: 16 coalesced 16B loads (L2-resident after first blocks)
    bf16x8 bfrag[2][4][2];
#pragma unroll
    for (int m = 0; m < 2; ++m)
#pragma unroll
        for (int t = 0; t < 4; ++t)
#pragma unroll
            for (int c = 0; c < 2; ++c)
                bfrag[m][t][c] = *(const bf16x8*)(wf + ((size_t)((m * 4 + t) * 2 + c) * 64 + lane) * 8);

    f32x4 acc[4];
#pragma unroll
    for (int t = 0; t < 4; ++t) {
        float bs = bgc[t * 16 + n] + bbi[t * 16 + n];
        acc[t] = (f32x4){bs, bs, bs, bs};
    }

    size_t abase = (size_t)(r0 + n) * EMB + quad * 8;
    bf16x8 as0 = *(const bf16x8*)(side_h + abase);
    bf16x8 as1 = *(const bf16x8*)(side_h + abase + 32);
    bf16x8 ae0 = *(const bf16x8*)(ego_h + abase);
    bf16x8 ae1 = *(const bf16x8*)(ego_h + abase + 32);
    bf16x8 ap0 = mul_bf(ae0, as0);
    bf16x8 ap1 = mul_bf(ae1, as1);

#pragma unroll
    for (int t = 0; t < 4; ++t) {
        acc[t] = __builtin_amdgcn_mfma_f32_16x16x32_bf16(as0, bfrag[0][t][0], acc[t], 0, 0, 0);
        acc[t] = __builtin_amdgcn_mfma_f32_16x16x32_bf16(as1, bfrag[0][t][1], acc[t], 0, 0, 0);
        acc[t] = __builtin_amdgcn_mfma_f32_16x16x32_bf16(ap0, bfrag[1][t][0], acc[t], 0, 0, 0);
        acc[t] = __builtin_amdgcn_mfma_f32_16x16x32_bf16(ap1, bfrag[1][t][1], acc[t], 0, 0, 0);
    }

    // epilogue: C/D layout col=lane&15, row=quad*4+reg (m89-verified)
#pragma unroll
    for (int t = 0; t < 4; ++t) {
#pragma unroll
        for (int i = 0; i < 4; ++i) {
            float v = acc[t][i];
            float o = v > 0.f ? v : 0.2f * v;
            size_t off = (size_t)(r0 + quad * 4 + i) * EMB + t * 16 + n;
            ego[off] = o;
            ego_h[off] = f2bf(o);
        }
    }
}

// gather batch rows of ego (f32), L2-normalize, write out cols [64*layer, ...)
__global__ void gather_norm(const int* __restrict__ users, const int* __restrict__ pos,
                            const int* __restrict__ neg, const float* __restrict__ ego,
                            float* __restrict__ out, int layer) {
    int b = blockIdx.x;
    int lane = threadIdx.x;
    int node = batch_node(users, pos, neg, b);
    float v = ego[(size_t)node * EMB + lane];
    float s = v * v;
#pragma unroll
    for (int off = 32; off > 0; off >>= 1) s += __shfl_xor(s, off);
    float n = fmaxf(sqrtf(s), 1e-12f);
    out[(size_t)b * 256 + layer * EMB + lane] = v / n;
}

extern "C" void kernel_launch(void* const* d_in, const int* in_sizes, int n_in,
                              void* d_out, int out_size, void* d_ws, size_t ws_size,
                              hipStream_t stream) {
    const int*   users    = (const int*)d_in[0];
    const int*   pos      = (const int*)d_in[1];
    const int*   neg      = (const int*)d_in[2];
    const int*   adj_row  = (const int*)d_in[3];
    const int*   adj_col  = (const int*)d_in[4];
    const float* adj_val  = (const float*)d_in[5];
    const float* user_emb = (const float*)d_in[6];
    const float* item_emb = (const float*)d_in[7];
    // d_in[8..19]: W_gc_0, b_gc_0, W_bi_0, b_bi_0, W_gc_1, ... (4 per layer)

    float*          ego     = (float*)d_ws;
    unsigned short* ego_h   = (unsigned short*)(ego + (size_t)N_NODES * EMB);
    unsigned short* side_h  = ego_h + (size_t)N_NODES * EMB;
    int*            row_ptr = (int*)(side_h + (size_t)N_NODES * EMB);
    unsigned short* wfrag   = (unsigned short*)(row_ptr + 200704);  // 16B-aligned
    float*          out     = (float*)d_out;

    build_row_ptr<<<(NNZ + 255) / 256, 256, 0, stream>>>(adj_row, row_ptr);
    concat_ego<<<(N_NODES * EMB + 255) / 256, 256, 0, stream>>>(user_emb, item_emb, ego, ego_h);
    prep_wfrags<<<48, 64, 0, stream>>>((const float*)d_in[8], (const float*)d_in[10],
                                       (const float*)d_in[12], (const float*)d_in[14],
                                       (const float*)d_in[16], (const float*)d_in[18], wfrag);
    gather_layer0<<<3 * BATCH, 64, 0, stream>>>(users, pos, neg, ego, out);

    for (int k = 0; k < 3; ++k) {
        const float* bgc = (const float*)d_in[9 + 4 * k];
        const float* bbi = (const float*)d_in[11 + 4 * k];
        spmm_csr<<<N_NODES / 4, 256, 0, stream>>>(row_ptr, adj_col, adj_val, ego_h, side_h);
        dense_mfma<<<N_NODES / 64, 256, 0, stream>>>(side_h, ego_h, ego,
                                                     wfrag + (size_t)k * 2 * 8 * 64 * 8, bgc, bbi);
        gather_norm<<<3 * BATCH, 64, 0, stream>>>(users, pos, neg, ego, out, k + 1);
    }
}

// Round 5
// 614.338 us; speedup vs baseline: 1.8870x; 1.0182x over previous
//
#include <hip/hip_runtime.h>

#define N_USER 100000
#define N_ITEM 100000
#define N_NODES 200000
#define NNZ 6400000
#define EMB 64
#define BATCH 1024

typedef __attribute__((ext_vector_type(8))) short bf16x8;   // 8 bf16 = 4 VGPRs
typedef __attribute__((ext_vector_type(4))) float f32x4;    // MFMA 16x16 acc

// ---------------------------------------------------------------------------
// Workspace layout (all bf16 state; no f32 mirror):
//   ego_h   : N_NODES*EMB bf16  (25.6 MB) master state (spmm gather + dense A)
//   side_h  : N_NODES*EMB bf16  (25.6 MB) spmm output
//   row_ptr : padded to 200704 ints       CSR row starts (adj_row is sorted)
//   wfrag   : 6*8*64*8 bf16     (48 KB)   weights pre-packed into B-fragments
// ---------------------------------------------------------------------------

// f32 -> bf16 (RNE), raw ushort bits
__device__ __forceinline__ unsigned short f2bf(float f) {
    unsigned int b = __builtin_bit_cast(unsigned int, f);
    b += 0x7FFFu + ((b >> 16) & 1u);
    return (unsigned short)(b >> 16);
}
__device__ __forceinline__ float bf2f(unsigned short u) {
    return __builtin_bit_cast(float, (unsigned int)u << 16);
}
__device__ __forceinline__ unsigned int pack2(float lo, float hi) {
    return ((unsigned int)f2bf(hi) << 16) | f2bf(lo);
}

// elementwise product of two bf16 fragments (A-layouts align), f32 math
__device__ __forceinline__ bf16x8 mul_bf(bf16x8 a, bf16x8 b) {
    bf16x8 r;
#pragma unroll
    for (int j = 0; j < 8; ++j) {
        float f = bf2f((unsigned short)a[j]) * bf2f((unsigned short)b[j]);
        r[j] = (short)f2bf(f);
    }
    return r;
}

// row_ptr[r] = lower_bound(adj_row, r); every r in [0, N_NODES] written once.
__global__ void build_row_ptr(const int* __restrict__ row, int* __restrict__ row_ptr) {
    int i = blockIdx.x * blockDim.x + threadIdx.x;
    if (i >= NNZ) return;
    int b = row[i];
    int a = (i == 0) ? -1 : row[i - 1];
    for (int r = a + 1; r <= b; ++r) row_ptr[r] = i;
    if (i == NNZ - 1) {
        for (int r = b + 1; r <= N_NODES; ++r) row_ptr[r] = NNZ;
    }
}

// ego_h = bf16([user_emb ; item_emb]); float4 in, 4xbf16 (uint2) out
__global__ void concat_ego(const float* __restrict__ ue, const float* __restrict__ ie,
                           unsigned short* __restrict__ ego_h) {
    int i = blockIdx.x * blockDim.x + threadIdx.x;   // float4 index
    const int nu4 = N_USER * EMB / 4;
    const int tot4 = N_NODES * EMB / 4;
    if (i >= tot4) return;
    float4 v = (i < nu4) ? ((const float4*)ue)[i] : ((const float4*)ie)[i - nu4];
    uint2 o;
    o.x = pack2(v.x, v.y);
    o.y = pack2(v.z, v.w);
    ((uint2*)ego_h)[i] = o;
}

// pack the 6 64x64 f32 weight matrices into MFMA B-fragment layout (bf16).
__global__ void prep_wfrags(const float* __restrict__ W0, const float* __restrict__ W1,
                            const float* __restrict__ W2, const float* __restrict__ W3,
                            const float* __restrict__ W4, const float* __restrict__ W5,
                            unsigned short* __restrict__ wfrag) {
    int m = blockIdx.x >> 3;
    int t = (blockIdx.x >> 1) & 3, c = blockIdx.x & 1;
    const float* W = m == 0 ? W0 : m == 1 ? W1 : m == 2 ? W2 : m == 3 ? W3 : m == 4 ? W4 : W5;
    int l = threadIdx.x, quad = l >> 4, n = l & 15;
    unsigned short* dst = wfrag + ((size_t)blockIdx.x * 64 + l) * 8;
#pragma unroll
    for (int j = 0; j < 8; ++j)
        dst[j] = f2bf(W[(c * 32 + quad * 8 + j) * 64 + t * 16 + n]);
}

__device__ __forceinline__ int batch_node(const int* users, const int* pos,
                                          const int* neg, int b) {
    int t = b >> 10, idx = b & 1023;
    if (t == 0) return users[idx];
    if (t == 1) return N_USER + pos[idx];
    return N_USER + neg[idx];
}

// layer-0 output columns: exact f32 from the original input embeddings
__global__ void gather_layer0(const int* __restrict__ users, const int* __restrict__ pos,
                              const int* __restrict__ neg, const float* __restrict__ ue,
                              const float* __restrict__ ie, float* __restrict__ out) {
    int b = blockIdx.x;
    int node = batch_node(users, pos, neg, b);
    float v = (node < N_USER) ? ue[(size_t)node * EMB + threadIdx.x]
                              : ie[(size_t)(node - N_USER) * EMB + threadIdx.x];
    out[(size_t)b * 256 + threadIdx.x] = v;
}

// CSR SpMM, quarter-wave gather: wave = 1 row; 16 lanes x uint2 (4 dims) cover
// the 64-dim row, so ONE dwordx2 gather serves 4 nnz (quarters q=0..3 handle
// nnz t..t+3). Chunk of 32 (col,val) staged coalesced (lanes &31), per-quarter
// broadcast via ds_bpermute (LDS pipe, const offset). 32-bit index math keeps
// the gather in saddr form (no 64-bit VGPR address chains).
__global__ __launch_bounds__(256) void spmm_csr(
        const int* __restrict__ row_ptr, const int* __restrict__ col,
        const float* __restrict__ val, const unsigned short* __restrict__ xh,
        unsigned short* __restrict__ yh) {
    int wave = (blockIdx.x * blockDim.x + threadIdx.x) >> 6;
    int lane = threadIdx.x & 63;
    if (wave >= N_NODES) return;
    int q = lane >> 4, p = lane & 15;
    int q4 = q << 2;
    unsigned p4 = (unsigned)p * 4u;
    int j0 = row_ptr[wave], j1 = row_ptr[wave + 1];
    float a0 = 0.f, a1 = 0.f, a2 = 0.f, a3 = 0.f;
    for (int j = j0; j < j1; j += 32) {
        int jl = j + (lane & 31);           // lanes 32..63 duplicate 0..31
        bool ok = jl < j1;
        int cc = ok ? __builtin_nontemporal_load(col + jl) : 0;
        int vv = ok ? __builtin_bit_cast(int, __builtin_nontemporal_load(val + jl))
                    : 0;
        int n = j1 - j;
#pragma unroll
        for (int g = 0; g < 4; ++g) {
            if (g * 8 >= n) break;          // wave-uniform exit
#pragma unroll
            for (int s = 0; s < 2; ++s) {
                const int t = g * 8 + s * 4;          // this step: nnz t..t+3
                int   ct = __builtin_amdgcn_ds_bpermute(q4 + t * 4, cc);
                float vt = __builtin_bit_cast(float,
                            __builtin_amdgcn_ds_bpermute(q4 + t * 4, vv));
                unsigned idx = (unsigned)ct * 64u + p4;   // ushort index
                uint2 d = *(const uint2*)(xh + idx);
                float f0 = __builtin_bit_cast(float, d.x << 16);
                float f1 = __builtin_bit_cast(float, d.x & 0xffff0000u);
                float f2 = __builtin_bit_cast(float, d.y << 16);
                float f3 = __builtin_bit_cast(float, d.y & 0xffff0000u);
                a0 = fmaf(vt, f0, a0);
                a1 = fmaf(vt, f1, a1);
                a2 = fmaf(vt, f2, a2);
                a3 = fmaf(vt, f3, a3);
            }
        }
    }
    // combine the 4 quarter-partials (lane p keeps dims 4p..4p+3)
    a0 += __shfl_xor(a0, 16); a0 += __shfl_xor(a0, 32);
    a1 += __shfl_xor(a1, 16); a1 += __shfl_xor(a1, 32);
    a2 += __shfl_xor(a2, 16); a2 += __shfl_xor(a2, 32);
    a3 += __shfl_xor(a3, 16); a3 += __shfl_xor(a3, 32);
    if (q == 0) {
        uint2 o;
        o.x = pack2(a0, a1);
        o.y = pack2(a2, a3);
        ((uint2*)(yh + (size_t)wave * EMB))[p] = o;   // 16 lanes x 8B = full row
    }
}

// MFMA dense layer: ego_h <- bf16(leaky_relu(side@Wgc + bgc + (ego*side)@Wbi + bbi)).
// Wave = 16 rows x 64 cols; 16 MFMA into one bias-initialized accumulator.
// In-place ego_h update safe: each row read+written by exactly one wave.
__global__ __launch_bounds__(256) void dense_mfma(
        const unsigned short* __restrict__ side_h,
        unsigned short* __restrict__ ego_h,
        const unsigned short* __restrict__ wf,   // this layer: [m][t][c][lane][8]
        const float* __restrict__ bgc, const float* __restrict__ bbi) {
    int wave = threadIdx.x >> 6;
    int lane = threadIdx.x & 63;
    int quad = lane >> 4, n = lane & 15;
    int r0 = blockIdx.x * 64 + wave * 16;

    bf16x8 bfrag[2][4][2];
#pragma unroll
    for (int m = 0; m < 2; ++m)
#pragma unroll
        for (int t = 0; t < 4; ++t)
#pragma unroll
            for (int c = 0; c < 2; ++c)
                bfrag[m][t][c] = *(const bf16x8*)(wf + ((size_t)((m * 4 + t) * 2 + c) * 64 + lane) * 8);

    f32x4 acc[4];
#pragma unroll
    for (int t = 0; t < 4; ++t) {
        float bs = bgc[t * 16 + n] + bbi[t * 16 + n];
        acc[t] = (f32x4){bs, bs, bs, bs};
    }

    size_t abase = (size_t)(r0 + n) * EMB + quad * 8;
    bf16x8 as0 = *(const bf16x8*)(side_h + abase);
    bf16x8 as1 = *(const bf16x8*)(side_h + abase + 32);
    bf16x8 ae0 = *(const bf16x8*)(ego_h + abase);
    bf16x8 ae1 = *(const bf16x8*)(ego_h + abase + 32);
    bf16x8 ap0 = mul_bf(ae0, as0);
    bf16x8 ap1 = mul_bf(ae1, as1);

#pragma unroll
    for (int t = 0; t < 4; ++t) {
        acc[t] = __builtin_amdgcn_mfma_f32_16x16x32_bf16(as0, bfrag[0][t][0], acc[t], 0, 0, 0);
        acc[t] = __builtin_amdgcn_mfma_f32_16x16x32_bf16(as1, bfrag[0][t][1], acc[t], 0, 0, 0);
        acc[t] = __builtin_amdgcn_mfma_f32_16x16x32_bf16(ap0, bfrag[1][t][0], acc[t], 0, 0, 0);
        acc[t] = __builtin_amdgcn_mfma_f32_16x16x32_bf16(ap1, bfrag[1][t][1], acc[t], 0, 0, 0);
    }

    // epilogue: C/D layout col=lane&15, row=quad*4+reg (m89-verified)
#pragma unroll
    for (int t = 0; t < 4; ++t) {
#pragma unroll
        for (int i = 0; i < 4; ++i) {
            float v = acc[t][i];
            float o = v > 0.f ? v : 0.2f * v;
            ego_h[(size_t)(r0 + quad * 4 + i) * EMB + t * 16 + n] = f2bf(o);
        }
    }
}

// gather batch rows of ego_h (bf16), L2-normalize, write out cols [64*layer,...)
__global__ void gather_norm(const int* __restrict__ users, const int* __restrict__ pos,
                            const int* __restrict__ neg,
                            const unsigned short* __restrict__ ego_h,
                            float* __restrict__ out, int layer) {
    int b = blockIdx.x;
    int lane = threadIdx.x;
    int node = batch_node(users, pos, neg, b);
    float v = bf2f(ego_h[(size_t)node * EMB + lane]);
    float s = v * v;
#pragma unroll
    for (int off = 32; off > 0; off >>= 1) s += __shfl_xor(s, off);
    float n = fmaxf(sqrtf(s), 1e-12f);
    out[(size_t)b * 256 + layer * EMB + lane] = v / n;
}

extern "C" void kernel_launch(void* const* d_in, const int* in_sizes, int n_in,
                              void* d_out, int out_size, void* d_ws, size_t ws_size,
                              hipStream_t stream) {
    const int*   users    = (const int*)d_in[0];
    const int*   pos      = (const int*)d_in[1];
    const int*   neg      = (const int*)d_in[2];
    const int*   adj_row  = (const int*)d_in[3];
    const int*   adj_col  = (const int*)d_in[4];
    const float* adj_val  = (const float*)d_in[5];
    const float* user_emb = (const float*)d_in[6];
    const float* item_emb = (const float*)d_in[7];
    // d_in[8..19]: W_gc_0, b_gc_0, W_bi_0, b_bi_0, W_gc_1, ... (4 per layer)

    unsigned short* ego_h   = (unsigned short*)d_ws;
    unsigned short* side_h  = ego_h + (size_t)N_NODES * EMB;
    int*            row_ptr = (int*)(side_h + (size_t)N_NODES * EMB);
    unsigned short* wfrag   = (unsigned short*)(row_ptr + 200704);  // 16B-aligned
    float*          out     = (float*)d_out;

    build_row_ptr<<<(NNZ + 255) / 256, 256, 0, stream>>>(adj_row, row_ptr);
    concat_ego<<<(N_NODES * EMB / 4 + 255) / 256, 256, 0, stream>>>(user_emb, item_emb, ego_h);
    prep_wfrags<<<48, 64, 0, stream>>>((const float*)d_in[8], (const float*)d_in[10],
                                       (const float*)d_in[12], (const float*)d_in[14],
                                       (const float*)d_in[16], (const float*)d_in[18], wfrag);
    gather_layer0<<<3 * BATCH, 64, 0, stream>>>(users, pos, neg, user_emb, item_emb, out);

    for (int k = 0; k < 3; ++k) {
        const float* bgc = (const float*)d_in[9 + 4 * k];
        const float* bbi = (const float*)d_in[11 + 4 * k];
        spmm_csr<<<N_NODES / 4, 256, 0, stream>>>(row_ptr, adj_col, adj_val, ego_h, side_h);
        dense_mfma<<<N_NODES / 64, 256, 0, stream>>>(side_h, ego_h,
                                                     wfrag + (size_t)k * 2 * 8 * 64 * 8, bgc, bbi);
        gather_norm<<<3 * BATCH, 64, 0, stream>>>(users, pos, neg, ego_h, out, k + 1);
    }
}